// Round 8
// baseline (47.861 us; speedup 1.0000x reference)
//
#include <hip/hip_runtime.h>

#define BATCH 16
#define NN 1000
#define DD 256
#define KMAX 512

#define META_STRIDE 2560   // ints per batch: inv1[1000], inv2[1000], order[512], U
#define AP 1024            // row stride (elements) of adjb(u8) and T(u8)

typedef unsigned char u8;
typedef __attribute__((ext_vector_type(4))) int i32x4;

#define LD4(p) (*(const float4*)(p))

// ---------------- meta body (shared by standalone + fused) ----------------
__device__ __forceinline__ void meta_body(
    int b, int t,
    const int* __restrict__ idx1, const int* __restrict__ idx2,
    const int* __restrict__ k1, const int* __restrict__ k2,
    int* __restrict__ meta) {
  __shared__ int sc[256];
  __shared__ int sU;
  int* inv1 = meta + (size_t)b * META_STRIDE;
  int* inv2 = inv1 + NN;
  int* order = inv2 + NN;
  int* Uptr = order + KMAX;
  const int* i1 = idx1 + (size_t)b * NN;
  const int* i2 = idx2 + (size_t)b * NN;
  for (int j = t; j < NN; j += 256) {
    inv1[i1[j]] = j;
    inv2[i2[j]] = j;
  }
  __syncthreads();
  int kk1 = k1[b], kk2 = k2[b];
  int base = t * 4;
  int un[4];
  int cnt = 0;
  for (int i = 0; i < 4; ++i) {
    int v = base + i;
    int u = 0;
    if (v < NN) u = (inv1[v] < kk1) || (inv2[v] < kk2);
    un[i] = u;
    cnt += u;
  }
  sc[t] = cnt;
  __syncthreads();
  for (int off = 1; off < 256; off <<= 1) {
    int v = (t >= off) ? sc[t - off] : 0;
    __syncthreads();
    sc[t] += v;
    __syncthreads();
  }
  int pref = sc[t] - cnt;
  for (int i = 0; i < 4; ++i)
    if (un[i]) order[pref++] = base + i;
  if (t == 255) {
    sU = sc[255];
    *Uptr = sc[255];
  }
  __syncthreads();
  int U = sU;
  for (int r = U + t; r < KMAX; r += 256) order[r] = 0;  // safe gather index
}

__global__ __launch_bounds__(256) void meta_kernel(
    const int* __restrict__ idx1, const int* __restrict__ idx2,
    const int* __restrict__ k1, const int* __restrict__ k2,
    int* __restrict__ meta) {
  meta_body(blockIdx.x, threadIdx.x, idx1, idx2, k1, k2, meta);
}

// ---------------- fp32 -> u8 pack ----------------
__device__ __forceinline__ unsigned int pack4u8(float4 f) {
  return (unsigned int)(u8)f.x | ((unsigned int)(u8)f.y << 8) |
         ((unsigned int)(u8)f.z << 16) | ((unsigned int)(u8)f.w << 24);
}

// conv body: 4 rows/block, 64 lanes/row, contiguous float4 loads
__device__ __forceinline__ void conv_rows(
    const float* __restrict__ adj, u8* __restrict__ adjb,
    int b_src, int b_dst, int r, int l) {
  const float* srcrow = adj + ((size_t)b_src * NN + r) * NN;
  u8* dstrow = adjb + ((size_t)b_dst * AP + r) * AP;
#pragma unroll
  for (int j = 0; j < 4; ++j) {
    int idx = l + 64 * j;            // float4 index, 0..255
    unsigned int w = 0;
    if (r < NN && idx < 250) w = pack4u8(LD4(srcrow + idx * 4));
    *(unsigned int*)(dstrow + idx * 4) = w;
  }
}

// ---------------- fused conv (adj f32 -> u8, padded 1024x1024) + meta ----------------
// blocks [0,4096): conv, XCD-pinned batch = (g&7)+8*(slot>>8); blocks [4096,4112): meta
__global__ __launch_bounds__(256) void convmeta_kernel(
    const float* __restrict__ adj, u8* __restrict__ adjb,
    const int* __restrict__ idx1, const int* __restrict__ idx2,
    const int* __restrict__ k1, const int* __restrict__ k2,
    int* __restrict__ meta) {
  int g = blockIdx.x;
  int tid = threadIdx.x;
  if (g >= 4096) {
    meta_body(g - 4096, tid, idx1, idx2, k1, k2, meta);
    return;
  }
  int xcd = g & 7, slot = g >> 3;
  int b = xcd + 8 * (slot >> 8);
  int r = (slot & 255) * 4 + (tid >> 6);
  conv_rows(adj, adjb, b, b, r, tid & 63);
}

// fallback conv (non-pinned, chunked)
__global__ __launch_bounds__(256) void conv_fb_kernel(
    const float* __restrict__ adj, u8* __restrict__ adjb, int bbase) {
  int bz = blockIdx.y;
  int tid = threadIdx.x;
  int r = blockIdx.x * 4 + (tid >> 6);
  conv_rows(adj, adjb, bbase + bz, bz, r, tid & 63);
}

// ---------------- feat: one output row (64 lanes, float4 each) ----------------
__device__ __forceinline__ void feat_row(
    const float* __restrict__ H1, const float* __restrict__ H2,
    const int* __restrict__ k1, const int* __restrict__ k2,
    const int* __restrict__ meta, float* __restrict__ outH,
    float* __restrict__ outMask, int b, int r, int l) {
  const int* inv1 = meta + (size_t)b * META_STRIDE;
  const int* inv2 = inv1 + NN;
  const int* order = inv2 + NN;
  int U = order[KMAX];
  float4* oH = (float4*)(outH + ((size_t)b * KMAX + r) * DD) + l;
  if (r >= U) {
    *oH = make_float4(0.f, 0.f, 0.f, 0.f);
    if (l == 0) outMask[(size_t)b * KMAX + r] = 0.f;
    return;
  }
  int v = order[r];
  int j1 = inv1[v];
  int j2 = inv2[v];
  bool in1 = j1 < k1[b];
  bool in2 = j2 < k2[b];
  const float4* h1 = (const float4*)(H1 + ((size_t)b * NN + j1) * DD) + l;
  const float4* h2 = (const float4*)(H2 + ((size_t)b * NN + j2) * DD) + l;
  float4 o;
  if (in1 && in2) {
    float4 a = *h1, c = *h2;
    o = make_float4(0.5f * (a.x + c.x), 0.5f * (a.y + c.y),
                    0.5f * (a.z + c.z), 0.5f * (a.w + c.w));
  } else if (in1) {
    o = *h1;
  } else {
    o = *h2;
  }
  *oH = o;
  if (l == 0) outMask[(size_t)b * KMAX + r] = 1.f;
}

__global__ __launch_bounds__(256) void feat_kernel(
    const float* __restrict__ H1, const float* __restrict__ H2,
    const int* __restrict__ k1, const int* __restrict__ k2,
    const int* __restrict__ meta,
    float* __restrict__ outH, float* __restrict__ outMask, int bbase) {
  int tid = threadIdx.x;
  int r = blockIdx.x * 4 + (tid >> 6);
  int b = blockIdx.y + bbase;
  feat_row(H1, H2, k1, k2, meta, outH, outMask, b, r, tid & 63);
}

// ---------------- Unified i8 MFMA GEMM, BK=128, ring-4 LDS pipeline ----------------
// WHICH==1: T[512][1024](u8) = gather(adjb, order) @ adjb      (BM=BN=64)
// WHICH==2: outAdj[512][512](f32) = T @ gather(adjb, order)^T  (BM=BN=64)
// 4 LDS buffer sets, stage tile t+3 at iter t, ONE barrier per kt, counted vmcnt.
template<int WHICH, bool PIN, bool FEAT>
__global__ __launch_bounds__(256) void mm_kernel(
    const u8* __restrict__ adjb, u8* __restrict__ Tb,
    const int* __restrict__ meta, float* __restrict__ outAdj,
    const float* __restrict__ H1, const float* __restrict__ H2,
    const int* __restrict__ k1, const int* __restrict__ k2,
    float* __restrict__ outH, float* __restrict__ outMask, int bbase) {
  constexpr int BM = 64, BN = 64;
  constexpr int MR = 2, NR = 2;
  constexpr int LA = 2, LB = 2;               // wave-instrs per tile per side
  constexpr int CT_TILES = (WHICH == 1 ? AP : KMAX) / BN;  // 16 / 8
  constexpr int RT_TILES = KMAX / BM;         // 8
  constexpr int TILES = RT_TILES * CT_TILES;  // 128 / 64
  constexpr int MMBLK = 8 * 2 * TILES;        // 2048 / 1024
  // NKT = 8 tiles of k=128

  int tid = threadIdx.x;

  // ---- feat tail blocks (PIN main path only) ----
  if (FEAT && PIN && (int)blockIdx.x >= MMBLK) {
    int g2 = blockIdx.x - MMBLK;        // [0, 1024)
    int xcd = g2 & 7;
    int slot = g2 >> 3;                 // 0..127
    int b = xcd + 8 * (slot >> 6);
    int rb = slot & 63;                 // 8 rows each
    int l = tid & 63;
#pragma unroll
    for (int pass = 0; pass < 2; ++pass) {
      int r = rb * 8 + pass * 4 + (tid >> 6);
      feat_row(H1, H2, k1, k2, meta, outH, outMask, b, r, l);
    }
    return;
  }

  int bz, rt, ct;
  if (PIN) {
    int g = blockIdx.x;
    int xcd = g & 7;
    int slot = g >> 3;                  // 0 .. 2*TILES-1
    bz = xcd + 8 * (slot / TILES);
    int tt = slot % TILES;
    rt = tt / CT_TILES;
    ct = tt % CT_TILES;
  } else {
    bz = blockIdx.z;
    rt = blockIdx.y;
    ct = blockIdx.x;
  }
  int b = PIN ? bz : (bz + bbase);

  const int* order = meta + (size_t)b * META_STRIDE + 2 * NN;
  int U = order[KMAX];
  int lane = tid & 63;
  int w = tid >> 6;
  int wr = w >> 1, wc = w & 1;

  __shared__ __align__(16) u8 As[4][BM * 128];
  __shared__ __align__(16) u8 Bs[4][BN * 128];
  __shared__ int sOrd[64];

  const u8* adjbB = adjb + (size_t)bz * AP * AP;
  const u8* TbB = Tb + (size_t)bz * KMAX * AP;

  bool active;
  if (WHICH == 1) {
    active = (rt * BM < U);
    if (!active) return;  // rows never consumed downstream
  } else {
    active = (rt * BM < U) && (ct * BN < U);
  }

  if (tid < 64) sOrd[tid] = order[((WHICH == 1) ? rt * BM : ct * BN) + tid];
  __syncthreads();

  i32x4 acc[MR][NR] = {};

#define WAITV(N) asm volatile("s_waitcnt vmcnt(%0)" :: "i"(N) : "memory")
#define BARx() do { asm volatile("" ::: "memory"); __builtin_amdgcn_s_barrier(); \
                    asm volatile("" ::: "memory"); } while (0)

#define STAGE(BI, KT)                                                          \
  {                                                                            \
    u8* sa_ = &As[(BI)][0];                                                    \
    u8* sb_ = &Bs[(BI)][0];                                                    \
    int k0 = (KT) * 128;                                                       \
    _Pragma("unroll")                                                          \
    for (int i = 0; i < LA; ++i) {                                             \
      int p = i * 256 + tid;                                                   \
      int r = p >> 3, cp = p & 7;                                              \
      int cs = cp ^ (r & 7);                                                   \
      const u8* src = (WHICH == 1)                                             \
          ? adjbB + (size_t)sOrd[r] * AP + k0 + cs * 16                        \
          : TbB + (size_t)(rt * BM + r) * AP + k0 + cs * 16;                   \
      u8* dst = sa_ + (size_t)(i * 256 + (tid & 192)) * 16;                    \
      __builtin_amdgcn_global_load_lds(                                        \
          (const __attribute__((address_space(1))) void*)src,                  \
          (__attribute__((address_space(3))) void*)dst, 16, 0, 0);             \
    }                                                                          \
    _Pragma("unroll")                                                          \
    for (int i = 0; i < LB; ++i) {                                             \
      int p = i * 256 + tid;                                                   \
      int r = p >> 3, cp = p & 7;                                              \
      int cs = cp ^ (r & 7);                                                   \
      const u8* src = (WHICH == 1)                                             \
          ? adjbB + (size_t)(ct * BN + r) * AP + k0 + cs * 16                  \
          : adjbB + (size_t)sOrd[r] * AP + k0 + cs * 16;                       \
      u8* dst = sb_ + (size_t)(i * 256 + (tid & 192)) * 16;                    \
      __builtin_amdgcn_global_load_lds(                                        \
          (const __attribute__((address_space(1))) void*)src,                  \
          (__attribute__((address_space(3))) void*)dst, 16, 0, 0);             \
    }                                                                          \
  }

#define COMPUTE128(BI)                                                         \
  {                                                                            \
    const u8* ca_ = &As[(BI)][0];                                              \
    const u8* cb_ = &Bs[(BI)][0];                                              \
    _Pragma("unroll")                                                          \
    for (int s = 0; s < 2; ++s) {                                              \
      i32x4 a[MR], bv[NR];                                                     \
      _Pragma("unroll")                                                        \
      for (int m = 0; m < MR; ++m) {                                           \
        int row = wr * (MR * 16) + m * 16 + (lane & 15);                       \
        int c = (s * 4 + (lane >> 4)) ^ (row & 7);                             \
        a[m] = *(const i32x4*)(ca_ + row * 128 + c * 16);                      \
      }                                                                        \
      _Pragma("unroll")                                                        \
      for (int n = 0; n < NR; ++n) {                                           \
        int row = wc * (NR * 16) + n * 16 + (lane & 15);                       \
        int c = (s * 4 + (lane >> 4)) ^ (row & 7);                             \
        bv[n] = *(const i32x4*)(cb_ + row * 128 + c * 16);                     \
      }                                                                        \
      __builtin_amdgcn_s_setprio(1);                                           \
      _Pragma("unroll")                                                        \
      for (int m = 0; m < MR; ++m)                                             \
        _Pragma("unroll")                                                      \
        for (int n = 0; n < NR; ++n)                                           \
          acc[m][n] = __builtin_amdgcn_mfma_i32_16x16x64_i8(a[m], bv[n],       \
                                                            acc[m][n], 0, 0, 0); \
      __builtin_amdgcn_s_setprio(0);                                           \
    }                                                                          \
  }

  if (active) {
    STAGE(0, 0);
    STAGE(1, 1);
    STAGE(2, 2);
#pragma unroll 1
    for (int t = 0; t < 5; ++t) {
      WAITV(8);                 // tile t landed (2 tiles still in flight)
      BARx();
      COMPUTE128(t & 3);
      STAGE((t + 3) & 3, t + 3);  // target buf read at iter t-1, safe after BARx
    }
    WAITV(8); BARx(); COMPUTE128(1);   // t=5
    WAITV(4); BARx(); COMPUTE128(2);   // t=6
    WAITV(0); BARx(); COMPUTE128(3);   // t=7
  }
#undef STAGE
#undef COMPUTE128
#undef WAITV
#undef BARx

  // ---- epilogue ----
  if (WHICH == 1) {
    u8* TbW = Tb + (size_t)bz * KMAX * AP;
#pragma unroll
    for (int m = 0; m < MR; ++m)
#pragma unroll
      for (int n = 0; n < NR; ++n)
#pragma unroll
        for (int i = 0; i < 4; ++i) {
          int row = rt * BM + wr * (MR * 16) + m * 16 + ((lane >> 4) << 2) + i;
          int col = ct * BN + wc * (NR * 16) + n * 16 + (lane & 15);
          TbW[(size_t)row * AP + col] = (u8)acc[m][n][i];
        }
  } else {
    float* O = outAdj + (size_t)b * KMAX * KMAX;
#pragma unroll
    for (int m = 0; m < MR; ++m)
#pragma unroll
      for (int n = 0; n < NR; ++n)
#pragma unroll
        for (int i = 0; i < 4; ++i) {
          int row = rt * BM + wr * (MR * 16) + m * 16 + ((lane >> 4) << 2) + i;
          int col = ct * BN + wc * (NR * 16) + n * 16 + (lane & 15);
          float v = (row < U && col < U) ? (float)acc[m][n][i] : 0.f;
          O[(size_t)row * KMAX + col] = v;
        }
  }
}

extern "C" void kernel_launch(void* const* d_in, const int* in_sizes, int n_in,
                              void* d_out, int out_size, void* d_ws, size_t ws_size,
                              hipStream_t stream) {
  const float* adj = (const float*)d_in[0];
  const float* H1 = (const float*)d_in[1];
  const float* H2 = (const float*)d_in[2];
  const int* idx1 = (const int*)d_in[3];
  const int* idx2 = (const int*)d_in[4];
  const int* k1 = (const int*)d_in[5];
  const int* k2 = (const int*)d_in[6];

  float* outH = (float*)d_out;                              // [B,KMAX,DD]
  float* outAdj = outH + (size_t)BATCH * KMAX * DD;         // [B,KMAX,KMAX]
  float* outMask = outAdj + (size_t)BATCH * KMAX * KMAX;    // [B,KMAX]

  int* meta = (int*)d_ws;
  size_t meta_bytes = (size_t)BATCH * META_STRIDE * sizeof(int);
  size_t meta_al = (meta_bytes + 255) & ~(size_t)255;

  size_t adjb_one = (size_t)AP * AP;          // 1 MB (u8)
  size_t T_one = (size_t)KMAX * AP;           // 512 KB (u8)
  size_t per_b = adjb_one + T_one;            // 1.5 MB

  int chunk = 1;
  if (ws_size > meta_al + per_b)
    chunk = (int)((ws_size - meta_al) / per_b);
  if (chunk > BATCH) chunk = BATCH;
  if (chunk < 1) chunk = 1;

  u8* adjb = (u8*)((char*)d_ws + meta_al);
  u8* Tb = adjb + (size_t)chunk * adjb_one;

  if (chunk == BATCH) {
    // fused conv + meta (independent), XCD-pinned
    convmeta_kernel<<<dim3(4096 + 16), 256, 0, stream>>>(adj, adjb, idx1, idx2,
                                                         k1, k2, meta);
    // mm1 grid: [0,2048) mm tiles (XCD-pinned), [2048,3072) feat tail
    mm_kernel<1, true, true><<<dim3(3072), 256, 0, stream>>>(
        adjb, Tb, meta, outAdj, H1, H2, k1, k2, outH, outMask, 0);
    mm_kernel<2, true, false><<<dim3(1024), 256, 0, stream>>>(
        adjb, Tb, meta, outAdj, H1, H2, k1, k2, outH, outMask, 0);
  } else {
    meta_kernel<<<dim3(BATCH), 256, 0, stream>>>(idx1, idx2, k1, k2, meta);
    feat_kernel<<<dim3(KMAX / 4, BATCH), 256, 0, stream>>>(H1, H2, k1, k2, meta,
                                                           outH, outMask, 0);
    for (int bb = 0; bb < BATCH; bb += chunk) {
      int nb = (BATCH - bb < chunk) ? (BATCH - bb) : chunk;
      conv_fb_kernel<<<dim3(256, nb), 256, 0, stream>>>(adj, adjb, bb);
      mm_kernel<1, false, false><<<dim3(16, 8, nb), 256, 0, stream>>>(
          adjb, Tb, meta, outAdj, H1, H2, k1, k2, outH, outMask, bb);
      mm_kernel<2, false, false><<<dim3(8, 8, nb), 256, 0, stream>>>(
          adjb, Tb, meta, outAdj, H1, H2, k1, k2, outH, outMask, bb);
    }
  }
}

// Round 9
// 39.610 us; speedup vs baseline: 1.2083x; 1.2083x over previous
//
#include <hip/hip_runtime.h>

#define BATCH 16
#define NN 1000
#define DD 256
#define KMAX 512

#define META_STRIDE 2560   // ints per batch: inv1[1000], inv2[1000], order[512], U
#define AP 1024            // row stride (elements) of adjb(u8) and T(u8)

typedef unsigned char u8;
typedef __attribute__((ext_vector_type(4))) int i32x4;

#define LD4(p) (*(const float4*)(p))

// ---------------- meta body (shared by standalone + fused) ----------------
__device__ __forceinline__ void meta_body(
    int b, int t,
    const int* __restrict__ idx1, const int* __restrict__ idx2,
    const int* __restrict__ k1, const int* __restrict__ k2,
    int* __restrict__ meta) {
  __shared__ int sc[256];
  __shared__ int sU;
  int* inv1 = meta + (size_t)b * META_STRIDE;
  int* inv2 = inv1 + NN;
  int* order = inv2 + NN;
  int* Uptr = order + KMAX;
  const int* i1 = idx1 + (size_t)b * NN;
  const int* i2 = idx2 + (size_t)b * NN;
  for (int j = t; j < NN; j += 256) {
    inv1[i1[j]] = j;
    inv2[i2[j]] = j;
  }
  __syncthreads();
  int kk1 = k1[b], kk2 = k2[b];
  int base = t * 4;
  int un[4];
  int cnt = 0;
  for (int i = 0; i < 4; ++i) {
    int v = base + i;
    int u = 0;
    if (v < NN) u = (inv1[v] < kk1) || (inv2[v] < kk2);
    un[i] = u;
    cnt += u;
  }
  sc[t] = cnt;
  __syncthreads();
  for (int off = 1; off < 256; off <<= 1) {
    int v = (t >= off) ? sc[t - off] : 0;
    __syncthreads();
    sc[t] += v;
    __syncthreads();
  }
  int pref = sc[t] - cnt;
  for (int i = 0; i < 4; ++i)
    if (un[i]) order[pref++] = base + i;
  if (t == 255) {
    sU = sc[255];
    *Uptr = sc[255];
  }
  __syncthreads();
  int U = sU;
  for (int r = U + t; r < KMAX; r += 256) order[r] = 0;  // safe gather index
}

__global__ __launch_bounds__(256) void meta_kernel(
    const int* __restrict__ idx1, const int* __restrict__ idx2,
    const int* __restrict__ k1, const int* __restrict__ k2,
    int* __restrict__ meta) {
  meta_body(blockIdx.x, threadIdx.x, idx1, idx2, k1, k2, meta);
}

// ---------------- fp32 -> u8 pack ----------------
__device__ __forceinline__ unsigned int pack4u8(float4 f) {
  return (unsigned int)(u8)f.x | ((unsigned int)(u8)f.y << 8) |
         ((unsigned int)(u8)f.z << 16) | ((unsigned int)(u8)f.w << 24);
}

// conv body: 4 rows/block, 64 lanes/row, CONTIGUOUS float4 loads (coalesced)
__device__ __forceinline__ void conv_rows(
    const float* __restrict__ adj, u8* __restrict__ adjb,
    int b_src, int b_dst, int r, int l) {
  const float* srcrow = adj + ((size_t)b_src * NN + r) * NN;
  u8* dstrow = adjb + ((size_t)b_dst * AP + r) * AP;
#pragma unroll
  for (int j = 0; j < 4; ++j) {
    int idx = l + 64 * j;            // float4 index, 0..255
    unsigned int w = 0;
    if (r < NN && idx < 250) w = pack4u8(LD4(srcrow + idx * 4));
    *(unsigned int*)(dstrow + idx * 4) = w;
  }
}

// ---------------- fused conv (adj f32 -> u8, padded 1024x1024) + meta ----------------
// blocks [0,4096): conv, XCD-pinned batch = (g&7)+8*(slot>>8); blocks [4096,4112): meta
__global__ __launch_bounds__(256) void convmeta_kernel(
    const float* __restrict__ adj, u8* __restrict__ adjb,
    const int* __restrict__ idx1, const int* __restrict__ idx2,
    const int* __restrict__ k1, const int* __restrict__ k2,
    int* __restrict__ meta) {
  int g = blockIdx.x;
  int tid = threadIdx.x;
  if (g >= 4096) {
    meta_body(g - 4096, tid, idx1, idx2, k1, k2, meta);
    return;
  }
  int xcd = g & 7, slot = g >> 3;
  int b = xcd + 8 * (slot >> 8);
  int r = (slot & 255) * 4 + (tid >> 6);
  conv_rows(adj, adjb, b, b, r, tid & 63);
}

// fallback conv (non-pinned, chunked)
__global__ __launch_bounds__(256) void conv_fb_kernel(
    const float* __restrict__ adj, u8* __restrict__ adjb, int bbase) {
  int bz = blockIdx.y;
  int tid = threadIdx.x;
  int r = blockIdx.x * 4 + (tid >> 6);
  conv_rows(adj, adjb, bbase + bz, bz, r, tid & 63);
}

// ---------------- feat: one output row (64 lanes, float4 each) ----------------
__device__ __forceinline__ void feat_row(
    const float* __restrict__ H1, const float* __restrict__ H2,
    const int* __restrict__ k1, const int* __restrict__ k2,
    const int* __restrict__ meta, float* __restrict__ outH,
    float* __restrict__ outMask, int b, int r, int l) {
  const int* inv1 = meta + (size_t)b * META_STRIDE;
  const int* inv2 = inv1 + NN;
  const int* order = inv2 + NN;
  int U = order[KMAX];
  float4* oH = (float4*)(outH + ((size_t)b * KMAX + r) * DD) + l;
  if (r >= U) {
    *oH = make_float4(0.f, 0.f, 0.f, 0.f);
    if (l == 0) outMask[(size_t)b * KMAX + r] = 0.f;
    return;
  }
  int v = order[r];
  int j1 = inv1[v];
  int j2 = inv2[v];
  bool in1 = j1 < k1[b];
  bool in2 = j2 < k2[b];
  const float4* h1 = (const float4*)(H1 + ((size_t)b * NN + j1) * DD) + l;
  const float4* h2 = (const float4*)(H2 + ((size_t)b * NN + j2) * DD) + l;
  float4 o;
  if (in1 && in2) {
    float4 a = *h1, c = *h2;
    o = make_float4(0.5f * (a.x + c.x), 0.5f * (a.y + c.y),
                    0.5f * (a.z + c.z), 0.5f * (a.w + c.w));
  } else if (in1) {
    o = *h1;
  } else {
    o = *h2;
  }
  *oH = o;
  if (l == 0) outMask[(size_t)b * KMAX + r] = 1.f;
}

__global__ __launch_bounds__(256) void feat_kernel(
    const float* __restrict__ H1, const float* __restrict__ H2,
    const int* __restrict__ k1, const int* __restrict__ k2,
    const int* __restrict__ meta,
    float* __restrict__ outH, float* __restrict__ outMask, int bbase) {
  int tid = threadIdx.x;
  int r = blockIdx.x * 4 + (tid >> 6);
  int b = blockIdx.y + bbase;
  feat_row(H1, H2, k1, k2, meta, outH, outMask, b, r, tid & 63);
}

// ---------------- Unified i8 MFMA GEMM, BK=128, counted-vmcnt dbuf ----------------
// WHICH==1: T[512][1024](u8) = gather(adjb, order) @ adjb      (BM=64, BN=128)
// WHICH==2: outAdj[512][512](f32) = T @ gather(adjb, order)^T  (BM=BN=64)
template<int WHICH, int BM, int BN, bool PIN, bool FEAT>
__global__ __launch_bounds__(256) void mm_kernel(
    const u8* __restrict__ adjb, u8* __restrict__ Tb,
    const int* __restrict__ meta, float* __restrict__ outAdj,
    const float* __restrict__ H1, const float* __restrict__ H2,
    const int* __restrict__ k1, const int* __restrict__ k2,
    float* __restrict__ outH, float* __restrict__ outMask, int bbase) {
  constexpr int MR = BM / 32;                 // 2
  constexpr int NR = BN / 32;                 // 4 or 2
  constexpr int LA = (BM * 128) / 4096;       // stage instrs per 128-k, A: 2
  constexpr int LB = (BN * 128) / 4096;       // 4 or 2
  constexpr int LL = LA + LB;                 // 6 or 4
  constexpr int CT_TILES = (WHICH == 1 ? AP : KMAX) / BN;  // 8
  constexpr int RT_TILES = KMAX / BM;         // 8
  constexpr int TILES = RT_TILES * CT_TILES;  // 64
  constexpr int MMBLK = 8 * 2 * TILES;        // 1024
  constexpr int NKT = AP / 128;               // 8

  int tid = threadIdx.x;

  // ---- feat tail blocks (PIN main path only) ----
  if (FEAT && PIN && (int)blockIdx.x >= MMBLK) {
    int g2 = blockIdx.x - MMBLK;        // [0, 1024)
    int xcd = g2 & 7;
    int slot = g2 >> 3;                 // 0..127
    int b = xcd + 8 * (slot >> 6);
    int rb = slot & 63;                 // 8 rows each
    int l = tid & 63;
#pragma unroll
    for (int pass = 0; pass < 2; ++pass) {
      int r = rb * 8 + pass * 4 + (tid >> 6);
      feat_row(H1, H2, k1, k2, meta, outH, outMask, b, r, l);
    }
    return;
  }

  int bz, rt, ct;
  if (PIN) {
    int g = blockIdx.x;
    int xcd = g & 7;
    int slot = g >> 3;                  // 0 .. 2*TILES-1
    bz = xcd + 8 * (slot / TILES);
    int tt = slot % TILES;
    rt = tt / CT_TILES;
    ct = tt % CT_TILES;
  } else {
    bz = blockIdx.z;
    rt = blockIdx.y;
    ct = blockIdx.x;
  }
  int b = PIN ? bz : (bz + bbase);

  const int* order = meta + (size_t)b * META_STRIDE + 2 * NN;
  int U = order[KMAX];
  int lane = tid & 63;
  int w = tid >> 6;
  int wr = w >> 1, wc = w & 1;

  __shared__ __align__(16) u8 A0[BM * 128];
  __shared__ __align__(16) u8 B0[BN * 128];
  __shared__ __align__(16) u8 A1[BM * 128];
  __shared__ __align__(16) u8 B1[BN * 128];
  __shared__ int sOrd[64];

  const u8* adjbB = adjb + (size_t)bz * AP * AP;
  const u8* TbB = Tb + (size_t)bz * KMAX * AP;

  bool active;
  if (WHICH == 1) {
    active = (rt * BM < U);
    if (!active) return;  // rows never consumed downstream
  } else {
    active = (rt * BM < U) && (ct * BN < U);
  }

  if (tid < 64) sOrd[tid] = order[((WHICH == 1) ? rt * BM : ct * BN) + tid];
  __syncthreads();

  i32x4 acc[MR][NR] = {};

#define WAITV(N) asm volatile("s_waitcnt vmcnt(%0)" :: "i"(N) : "memory")
#define BARx() do { asm volatile("" ::: "memory"); __builtin_amdgcn_s_barrier(); \
                    asm volatile("" ::: "memory"); } while (0)

#define STAGE(ABUF, BBUF, KT)                                                  \
  {                                                                            \
    int k0 = (KT) * 128;                                                       \
    _Pragma("unroll")                                                          \
    for (int i = 0; i < LA; ++i) {                                             \
      int p = i * 256 + tid;                                                   \
      int r = p >> 3, cp = p & 7;                                              \
      int cs = cp ^ (r & 7);                                                   \
      const u8* src = (WHICH == 1)                                             \
          ? adjbB + (size_t)sOrd[r] * AP + k0 + cs * 16                        \
          : TbB + (size_t)(rt * BM + r) * AP + k0 + cs * 16;                   \
      u8* dst = (ABUF) + (size_t)(i * 256 + (tid & 192)) * 16;                 \
      __builtin_amdgcn_global_load_lds(                                        \
          (const __attribute__((address_space(1))) void*)src,                  \
          (__attribute__((address_space(3))) void*)dst, 16, 0, 0);             \
    }                                                                          \
    _Pragma("unroll")                                                          \
    for (int i = 0; i < LB; ++i) {                                             \
      int p = i * 256 + tid;                                                   \
      int r = p >> 3, cp = p & 7;                                              \
      int cs = cp ^ (r & 7);                                                   \
      const u8* src = (WHICH == 1)                                             \
          ? adjbB + (size_t)(ct * BN + r) * AP + k0 + cs * 16                  \
          : adjbB + (size_t)sOrd[r] * AP + k0 + cs * 16;                       \
      u8* dst = (BBUF) + (size_t)(i * 256 + (tid & 192)) * 16;                 \
      __builtin_amdgcn_global_load_lds(                                        \
          (const __attribute__((address_space(1))) void*)src,                  \
          (__attribute__((address_space(3))) void*)dst, 16, 0, 0);             \
    }                                                                          \
  }

#define COMPUTE128(ABUF, BBUF)                                                 \
  {                                                                            \
    _Pragma("unroll")                                                          \
    for (int s = 0; s < 2; ++s) {                                              \
      i32x4 a[MR], bv[NR];                                                     \
      _Pragma("unroll")                                                        \
      for (int m = 0; m < MR; ++m) {                                           \
        int row = wr * (MR * 16) + m * 16 + (lane & 15);                       \
        int c = (s * 4 + (lane >> 4)) ^ (row & 7);                             \
        a[m] = *(const i32x4*)((ABUF) + row * 128 + c * 16);                   \
      }                                                                        \
      _Pragma("unroll")                                                        \
      for (int n = 0; n < NR; ++n) {                                           \
        int row = wc * (NR * 16) + n * 16 + (lane & 15);                       \
        int c = (s * 4 + (lane >> 4)) ^ (row & 7);                             \
        bv[n] = *(const i32x4*)((BBUF) + row * 128 + c * 16);                  \
      }                                                                        \
      __builtin_amdgcn_s_setprio(1);                                           \
      _Pragma("unroll")                                                        \
      for (int m = 0; m < MR; ++m)                                             \
        _Pragma("unroll")                                                      \
        for (int n = 0; n < NR; ++n)                                           \
          acc[m][n] = __builtin_amdgcn_mfma_i32_16x16x64_i8(a[m], bv[n],       \
                                                            acc[m][n], 0, 0, 0); \
      __builtin_amdgcn_s_setprio(0);                                           \
    }                                                                          \
  }

  if (active) {
    STAGE(A0, B0, 0);
    STAGE(A1, B1, 1);
#pragma unroll 1
    for (int t = 0; t < NKT - 2; t += 2) {
      WAITV(LL);            // own tile-t loads done (t+1 still in flight)
      BARx();               // all waves' tile-t data landed
      COMPUTE128(A0, B0);
      BARx();               // all waves done reading A0/B0
      STAGE(A0, B0, t + 2);
      WAITV(LL);
      BARx();
      COMPUTE128(A1, B1);
      BARx();
      STAGE(A1, B1, t + 3);
    }
    WAITV(LL);
    BARx();
    COMPUTE128(A0, B0);     // tile NKT-2
    WAITV(0);
    BARx();
    COMPUTE128(A1, B1);     // tile NKT-1
  }
#undef STAGE
#undef COMPUTE128
#undef WAITV
#undef BARx

  // ---- epilogue ----
  if (WHICH == 1) {
    u8* TbW = Tb + (size_t)bz * KMAX * AP;
#pragma unroll
    for (int m = 0; m < MR; ++m)
#pragma unroll
      for (int n = 0; n < NR; ++n)
#pragma unroll
        for (int i = 0; i < 4; ++i) {
          int row = rt * BM + wr * (MR * 16) + m * 16 + ((lane >> 4) << 2) + i;
          int col = ct * BN + wc * (NR * 16) + n * 16 + (lane & 15);
          TbW[(size_t)row * AP + col] = (u8)acc[m][n][i];
        }
  } else {
    float* O = outAdj + (size_t)b * KMAX * KMAX;
#pragma unroll
    for (int m = 0; m < MR; ++m)
#pragma unroll
      for (int n = 0; n < NR; ++n)
#pragma unroll
        for (int i = 0; i < 4; ++i) {
          int row = rt * BM + wr * (MR * 16) + m * 16 + ((lane >> 4) << 2) + i;
          int col = ct * BN + wc * (NR * 16) + n * 16 + (lane & 15);
          float v = (row < U && col < U) ? (float)acc[m][n][i] : 0.f;
          O[(size_t)row * KMAX + col] = v;
        }
  }
}

extern "C" void kernel_launch(void* const* d_in, const int* in_sizes, int n_in,
                              void* d_out, int out_size, void* d_ws, size_t ws_size,
                              hipStream_t stream) {
  const float* adj = (const float*)d_in[0];
  const float* H1 = (const float*)d_in[1];
  const float* H2 = (const float*)d_in[2];
  const int* idx1 = (const int*)d_in[3];
  const int* idx2 = (const int*)d_in[4];
  const int* k1 = (const int*)d_in[5];
  const int* k2 = (const int*)d_in[6];

  float* outH = (float*)d_out;                              // [B,KMAX,DD]
  float* outAdj = outH + (size_t)BATCH * KMAX * DD;         // [B,KMAX,KMAX]
  float* outMask = outAdj + (size_t)BATCH * KMAX * KMAX;    // [B,KMAX]

  int* meta = (int*)d_ws;
  size_t meta_bytes = (size_t)BATCH * META_STRIDE * sizeof(int);
  size_t meta_al = (meta_bytes + 255) & ~(size_t)255;

  size_t adjb_one = (size_t)AP * AP;          // 1 MB (u8)
  size_t T_one = (size_t)KMAX * AP;           // 512 KB (u8)
  size_t per_b = adjb_one + T_one;            // 1.5 MB

  int chunk = 1;
  if (ws_size > meta_al + per_b)
    chunk = (int)((ws_size - meta_al) / per_b);
  if (chunk > BATCH) chunk = BATCH;
  if (chunk < 1) chunk = 1;

  u8* adjb = (u8*)((char*)d_ws + meta_al);
  u8* Tb = adjb + (size_t)chunk * adjb_one;

  if (chunk == BATCH) {
    // fused conv + meta (independent), XCD-pinned
    convmeta_kernel<<<dim3(4096 + 16), 256, 0, stream>>>(adj, adjb, idx1, idx2,
                                                         k1, k2, meta);
    // mm1 grid: [0,1024) mm tiles (XCD-pinned), [1024,2048) feat tail
    mm_kernel<1, 64, 128, true, true><<<dim3(2048), 256, 0, stream>>>(
        adjb, Tb, meta, outAdj, H1, H2, k1, k2, outH, outMask, 0);
    mm_kernel<2, 64, 64, true, false><<<dim3(1024), 256, 0, stream>>>(
        adjb, Tb, meta, outAdj, H1, H2, k1, k2, outH, outMask, 0);
  } else {
    meta_kernel<<<dim3(BATCH), 256, 0, stream>>>(idx1, idx2, k1, k2, meta);
    feat_kernel<<<dim3(KMAX / 4, BATCH), 256, 0, stream>>>(H1, H2, k1, k2, meta,
                                                           outH, outMask, 0);
    for (int bb = 0; bb < BATCH; bb += chunk) {
      int nb = (BATCH - bb < chunk) ? (BATCH - bb) : chunk;
      conv_fb_kernel<<<dim3(256, nb), 256, 0, stream>>>(adj, adjb, bb);
      mm_kernel<1, 64, 128, false, false><<<dim3(8, 8, nb), 256, 0, stream>>>(
          adjb, Tb, meta, outAdj, H1, H2, k1, k2, outH, outMask, bb);
      mm_kernel<2, 64, 64, false, false><<<dim3(8, 8, nb), 256, 0, stream>>>(
          adjb, Tb, meta, outAdj, H1, H2, k1, k2, outH, outMask, bb);
    }
  }
}